// Round 9
// baseline (342.283 us; speedup 1.0000x reference)
//
#include <hip/hip_runtime.h>
#include <stdint.h>

typedef unsigned long long u64;
typedef int v4i  __attribute__((ext_vector_type(4)));
typedef int v16i __attribute__((ext_vector_type(16)));

#define PP  784
#define NHW 25088

// ---------------------------------------------------------------------------
// prepw: binarize weights into MFMA-B fragment layout + zero stats.
// wq layout: [t][ob=o>>5][kc=k>>5][kh=(k>>4)&1][ol=o&31][k&15] i8 (+-1)
//   -> B-frag load for (t,ntile,kc) is one contiguous 1KB dwordx4 per wave.
// grid (2 which, 256 o), 256 thr (= cin).
// ---------------------------------------------------------------------------
__global__ __launch_bounds__(256) void prepw(const float* __restrict__ w1, const float* __restrict__ w2,
        signed char* __restrict__ wq1, signed char* __restrict__ wq2,
        int* s1i, u64* s1q, double* s2s, double* s2q) {
    int which = blockIdx.x, o = blockIdx.y, cin = threadIdx.x;
    if (which == 0) {
        if (o == 0) s1i[cin] = 0;
        else if (o == 1) s1q[cin] = 0ull;
        else if (o == 2) s2s[cin] = 0.0;
        else if (o == 3) s2q[cin] = 0.0;
    }
    const float* w = which ? w2 : w1;
    signed char* wq = which ? wq2 : wq1;
    int kc = cin >> 5, kh = (cin >> 4) & 1, bx = cin & 15;
    size_t base = (size_t)kc * 1024 + (size_t)kh * 512 + (size_t)(o & 31) * 16 + bx;
    int ob = o >> 5;
#pragma unroll
    for (int t = 0; t < 9; ++t) {
        float val = w[((size_t)o * 256 + cin) * 9 + t];
        wq[(size_t)(t * 8 + ob) * 8192 + base] = (val > 0.0f) ? (signed char)1 : (signed char)-1;
    }
}

// ---------------------------------------------------------------------------
// prepx: binarize x (NCHW f32) -> xq (NHWC i8 +-1) via LDS transpose.
// grid (13 pt, 32 n), 256 thr. Reads coalesced (lane over p), LDS u32 tile
// [64p][68 words] (272B stride), writes 16B/thread coalesced.
// ---------------------------------------------------------------------------
__global__ __launch_bounds__(256) void prepx(const float* __restrict__ x, signed char* __restrict__ xq) {
    __shared__ __align__(16) int tT[64 * 68];
    int pt = blockIdx.x, n = blockIdx.y;
    int tid = threadIdx.x, lane = tid & 63, wv = tid >> 6;
    int p0 = pt * 64;
    int p = p0 + lane, pc = p < PP ? p : (PP - 1);
#pragma unroll 1
    for (int pp = 0; pp < 16; ++pp) {
        int cb = pp * 16 + wv * 4;
        unsigned word = 0;
#pragma unroll
        for (int j = 0; j < 4; ++j) {
            float val = x[((size_t)n * 256 + cb + j) * PP + pc];
            unsigned byte = (val > 0.0f) ? 0x01u : 0xFFu;
            word |= byte << (8 * j);
        }
        tT[lane * 68 + pp * 4 + wv] = (int)word;
    }
    __syncthreads();
#pragma unroll 1
    for (int pass = 0; pass < 4; ++pass) {
        int s = tid & 15, pq = tid >> 4;
        int pl = pass * 16 + pq;
        int pg = p0 + pl;
        if (pg < PP) {
            v4i w = *(const v4i*)&tT[pl * 68 + s * 4];
            *(v4i*)(xq + ((size_t)n * PP + pg) * 256 + s * 16) = w;
        }
    }
}

// ---------------------------------------------------------------------------
// mconv: binarized 3x3 conv as 9 accumulated i8 GEMMs on the matrix cores.
// grid (196 Mtiles of 128 flat pixels, 4 Nslices of 64 ch), 256 thr (4 waves).
// Wave wid owns 32 pixels x 64 ch = 2 C-tiles (mfma_i32_32x32x32_i8).
// A: flat pixel window [p0-32, p0+160) staged in LDS, 272B row stride +
//    16B-slot XOR swizzle (conflict-free); invalid taps -> zero slot.
// B: contiguous 1KB fragment loads from pre-swizzled wq (L2-resident).
// Output v: NHWC i16. STATS=1: fused exact int BN1 stats via shfl+atomics.
// ---------------------------------------------------------------------------
template<int STATS>
__global__ __launch_bounds__(256) void mconv(const signed char* __restrict__ xq,
        const signed char* __restrict__ wq, short* __restrict__ v,
        int* __restrict__ s1i, u64* __restrict__ s1q) {
    __shared__ __align__(16) signed char lin[52240];   // 192*272 + 16 zero slot
    int tid = threadIdx.x, lane = tid & 63, wid = tid >> 6;
    int kh = lane >> 5, l31 = lane & 31;
    int p0 = blockIdx.x * 128, nbase = blockIdx.y * 64;
    int ps0 = p0 - 32;

    for (int idx = tid; idx < 3072; idx += 256) {      // stage 192 pixels x 256B
        int fpl = idx >> 4, s = idx & 15;
        int fp = ps0 + fpl;
        fp = fp < 0 ? 0 : (fp > NHW - 1 ? NHW - 1 : fp);
        v4i w = *(const v4i*)(xq + (size_t)fp * 256 + s * 16);
        *(v4i*)(lin + fpl * 272 + ((s ^ (fpl & 15)) << 4)) = w;
    }
    if (tid < 4) ((int*)(lin + 52224))[tid] = 0;       // zero slot for masked taps
    __syncthreads();

    int p = p0 + wid * 32 + l31;                       // A-row flat pixel
    int pm = p % PP;
    int r = pm / 28, c = pm - r * 28;
    int psl = p - ps0;
    int nb2 = nbase >> 5;
    v16i acc0 = {}; v16i acc1 = {};

#pragma unroll 1
    for (int t = 0; t < 9; ++t) {
        int dr = t / 3, dc = t - dr * 3;
        bool ok = ((unsigned)(c + dc - 1) < 28u) && ((unsigned)(r + dr - 1) < 28u);
        int pslT = psl + (dr - 1) * 28 + (dc - 1);
        int abase = pslT * 272, m15 = pslT & 15;
        const signed char* wb0 = wq + (size_t)(t * 8 + nb2) * 8192 + (size_t)kh * 512 + (size_t)l31 * 16;
        const signed char* wb1 = wb0 + 8192;
#pragma unroll
        for (int kc = 0; kc < 8; ++kc) {
            int aoff = ok ? (abase + ((((kc * 2 + kh) ^ m15)) << 4)) : 52224;
            v4i a  = *(const v4i*)(lin + aoff);
            v4i b0 = *(const v4i*)(wb0 + kc * 1024);
            v4i b1 = *(const v4i*)(wb1 + kc * 1024);
            acc0 = __builtin_amdgcn_mfma_i32_32x32x32_i8(a, b0, acc0, 0, 0, 0);
            acc1 = __builtin_amdgcn_mfma_i32_32x32x32_i8(a, b1, acc1, 0, 0, 0);
        }
    }

    // writeback: C/D layout col=lane&31 (ch), row=(j&3)+8*(j>>2)+4*kh (pixel)
    {
        size_t prow = (size_t)(p0 + wid * 32);
        int ch0 = nbase + l31;
#pragma unroll
        for (int j = 0; j < 16; ++j) {
            int row = (j & 3) + 8 * (j >> 2) + 4 * kh;
            size_t off = (prow + row) * 256;
            v[off + ch0]      = (short)acc0[j];
            v[off + ch0 + 32] = (short)acc1[j];
        }
    }
    if (STATS) {
        int ss0 = 0, qq0 = 0, ss1 = 0, qq1 = 0;
#pragma unroll
        for (int j = 0; j < 16; ++j) {
            ss0 += acc0[j]; qq0 += acc0[j] * acc0[j];
            ss1 += acc1[j]; qq1 += acc1[j] * acc1[j];
        }
        ss0 += __shfl_xor(ss0, 32); qq0 += __shfl_xor(qq0, 32);
        ss1 += __shfl_xor(ss1, 32); qq1 += __shfl_xor(qq1, 32);
        if (lane < 32) {
            atomicAdd(&s1i[nbase + lane], ss0);
            atomicAdd(&s1q[nbase + lane], (u64)(unsigned)qq0);
            atomicAdd(&s1i[nbase + 32 + lane], ss1);
            atomicAdd(&s1q[nbase + 32 + lane], (u64)(unsigned)qq1);
        }
    }
}

// ---------------------------------------------------------------------------
// repack: sign(BN1(v1)) -> xq i8 (+-1), NHWC. BN1 params inline from exact
// int stats. grid (98 of 8 pixels, 32 n), 256 thr.
// ---------------------------------------------------------------------------
__global__ __launch_bounds__(256) void repack(const short* __restrict__ v,
        const int* __restrict__ s1i, const u64* __restrict__ s1q,
        const float* __restrict__ gamma, const float* __restrict__ beta,
        signed char* __restrict__ xq) {
    __shared__ float ash[256], bsh[256];
    int tid = threadIdx.x;
    {
        double mean = (double)s1i[tid] * (1.0 / NHW);
        double msq  = (double)s1q[tid] * (1.0 / NHW);
        double var  = msq - mean * mean;
        double istd = 1.0 / sqrt(var + 1e-5);
        double ad   = (double)gamma[tid] * istd;
        ash[tid] = (float)ad;
        bsh[tid] = (float)((double)beta[tid] - mean * ad);
    }
    __syncthreads();
    int n = blockIdx.y;
    int p = blockIdx.x * 8 + (tid >> 5), s8 = tid & 31;
    size_t base = ((size_t)n * PP + p) * 256 + s8 * 8;
    ulonglong2 raw = *(const ulonglong2*)(v + base);
    const short* sp = (const short*)&raw;
    u64 outb = 0;
#pragma unroll
    for (int j = 0; j < 8; ++j) {
        int cc = s8 * 8 + j;
        float y = fmaf(ash[cc], (float)sp[j], bsh[cc]);
        u64 byte = (y > 0.0f) ? 0x01ull : 0xFFull;
        outb |= byte << (8 * j);
    }
    *(u64*)(xq + base) = outb;
}

// ---------------------------------------------------------------------------
// stats2: per-channel f64 stats of (v2 + x); v NHWC via LDS transpose,
// x NCHW coalesced. grid (13 pt, 32 n), 256 thr.
// ---------------------------------------------------------------------------
__global__ __launch_bounds__(256) void stats2(const short* __restrict__ v, const float* __restrict__ x,
        double* __restrict__ s2s, double* __restrict__ s2q) {
    __shared__ short t[64 * 66];
    int pt = blockIdx.x, n = blockIdx.y, tid = threadIdx.x;
    int p0 = pt * 64;
    int pl = tid & 63, wv = tid >> 6;
    int p = p0 + pl; bool okp = p < PP;
#pragma unroll 1
    for (int ct = 0; ct < 4; ++ct) {
        for (int idx = tid; idx < 4096; idx += 256) {
            int i = idx >> 6, cl = idx & 63;
            int pi = p0 + i;
            t[i * 66 + cl] = (pi < PP) ? v[((size_t)n * PP + pi) * 256 + ct * 64 + cl] : (short)0;
        }
        __syncthreads();
#pragma unroll 1
        for (int cq = 0; cq < 16; ++cq) {
            int cl = cq * 4 + wv;
            int cch = ct * 64 + cl;
            float u = okp ? ((float)t[pl * 66 + cl] + x[((size_t)n * 256 + cch) * PP + p]) : 0.0f;
            double sd = (double)u, qd = (double)u * (double)u;
            for (int d = 32; d; d >>= 1) { sd += __shfl_down(sd, d); qd += __shfl_down(qd, d); }
            if (pl == 0) { atomicAdd(&s2s[cch], sd); atomicAdd(&s2q[cch], qd); }
        }
        __syncthreads();
    }
}

// ---------------------------------------------------------------------------
// finalize: out = clip(sc*(v2+x)+bi, -1, 1); BN2 inline; NHWC v -> NCHW out
// via LDS transpose. grid (4 ct, 13 pt, 32 n), 256 thr.
// ---------------------------------------------------------------------------
__global__ __launch_bounds__(256) void finalize(const short* __restrict__ v, const float* __restrict__ x,
        const double* __restrict__ s2s, const double* __restrict__ s2q,
        const float* __restrict__ gamma, const float* __restrict__ beta,
        float* __restrict__ out) {
    __shared__ short t[64 * 66];
    __shared__ float scs[64], bis[64];
    int ct = blockIdx.x, pt = blockIdx.y, n = blockIdx.z, tid = threadIdx.x;
    int c0 = ct * 64, p0 = pt * 64;
    if (tid < 64) {
        int cch = c0 + tid;
        double mean = s2s[cch] * (1.0 / NHW);
        double msq  = s2q[cch] * (1.0 / NHW);
        double var  = msq - mean * mean;
        double istd = 1.0 / sqrt(var + 1e-5);
        double ad   = (double)gamma[cch] * istd;
        scs[tid] = (float)ad;
        bis[tid] = (float)((double)beta[cch] - mean * ad);
    }
    for (int idx = tid; idx < 4096; idx += 256) {
        int i = idx >> 6, cl = idx & 63;
        int pi = p0 + i;
        t[i * 66 + cl] = (pi < PP) ? v[((size_t)n * PP + pi) * 256 + c0 + cl] : (short)0;
    }
    __syncthreads();
    int pl = tid & 63;
    int p = p0 + pl;
    if (p < PP) {
        for (int cl = tid >> 6; cl < 64; cl += 4) {
            int cch = c0 + cl;
            float val = (float)t[pl * 66 + cl] + x[((size_t)n * 256 + cch) * PP + p];
            float rr = fmaf(scs[cl], val, bis[cl]);
            rr = fminf(fmaxf(rr, -1.0f), 1.0f);
            out[((size_t)n * 256 + cch) * PP + p] = rr;
        }
    }
}

// ---------------------------------------------------------------------------
extern "C" void kernel_launch(void* const* d_in, const int* in_sizes, int n_in,
                              void* d_out, int out_size, void* d_ws, size_t ws_size,
                              hipStream_t stream) {
    (void)in_sizes; (void)n_in; (void)out_size; (void)ws_size;
    const float* x   = (const float*)d_in[0];
    const float* w1  = (const float*)d_in[1];
    const float* g1  = (const float*)d_in[2];
    const float* b1  = (const float*)d_in[3];
    const float* w2  = (const float*)d_in[4];
    const float* g2  = (const float*)d_in[5];
    const float* b2  = (const float*)d_in[6];
    float* out = (float*)d_out;

    // scratch in d_out (consumed before finalize overwrites it):
    signed char* xq  = (signed char*)d_out;                 //  6,422,528 B
    signed char* wq1 = (signed char*)d_out + 6422528;       //    589,824 B
    signed char* wq2 = (signed char*)d_out + 7012352;       //    589,824 B (end 7.6MB < 25.7MB)
    // d_ws:
    char* ws = (char*)d_ws;
    short*  v   = (short*)ws;                               // 12,845,056 B
    int*    s1i = (int*)(ws + 12845056);                    //      1,024 B
    u64*    s1q = (u64*)(ws + 12846080);                    //      2,048 B
    double* s2s = (double*)(ws + 12848128);                 //      2,048 B
    double* s2q = (double*)(ws + 12850176);                 //      2,048 B

    prepw<<<dim3(2, 256), 256, 0, stream>>>(w1, w2, wq1, wq2, s1i, s1q, s2s, s2q);
    prepx<<<dim3(13, 32), 256, 0, stream>>>(x, xq);
    mconv<1><<<dim3(196, 4), 256, 0, stream>>>(xq, wq1, v, s1i, s1q);
    repack<<<dim3(98, 32), 256, 0, stream>>>(v, s1i, s1q, g1, b1, xq);
    mconv<0><<<dim3(196, 4), 256, 0, stream>>>(xq, wq2, v, s1i, s1q);
    stats2<<<dim3(13, 32), 256, 0, stream>>>(v, x, s2s, s2q);
    finalize<<<dim3(4, 13, 32), 256, 0, stream>>>(v, x, s2s, s2q, g2, b2, out);
}

// Round 10
// 155.677 us; speedup vs baseline: 2.1987x; 2.1987x over previous
//
#include <hip/hip_runtime.h>
#include <stdint.h>

typedef unsigned long long u64;
typedef int v4i  __attribute__((ext_vector_type(4)));
typedef int v16i __attribute__((ext_vector_type(16)));

#define PP  784
#define NHW 25088

// ---------------------------------------------------------------------------
// prepw: binarize weights into MFMA-B fragment layout + zero stats.
// wq layout: [t][ob=o>>5][kc=k>>5][kh=(k>>4)&1][ol=o&31][k&15] i8 (+-1)
//   -> B-frag load for (t,ntile,kc) is one contiguous 1KB dwordx4 per wave.
// grid (2 which, 256 o), 256 thr (= cin).
// ---------------------------------------------------------------------------
__global__ __launch_bounds__(256) void prepw(const float* __restrict__ w1, const float* __restrict__ w2,
        signed char* __restrict__ wq1, signed char* __restrict__ wq2,
        int* s1i, u64* s1q) {
    int which = blockIdx.x, o = blockIdx.y, cin = threadIdx.x;
    if (which == 0) {
        if (o == 0) s1i[cin] = 0;
        else if (o == 1) s1q[cin] = 0ull;
    }
    const float* w = which ? w2 : w1;
    signed char* wq = which ? wq2 : wq1;
    int kc = cin >> 5, kh = (cin >> 4) & 1, bx = cin & 15;
    size_t base = (size_t)kc * 1024 + (size_t)kh * 512 + (size_t)(o & 31) * 16 + bx;
    int ob = o >> 5;
#pragma unroll
    for (int t = 0; t < 9; ++t) {
        float val = w[((size_t)o * 256 + cin) * 9 + t];
        wq[(size_t)(t * 8 + ob) * 8192 + base] = (val > 0.0f) ? (signed char)1 : (signed char)-1;
    }
}

// ---------------------------------------------------------------------------
// prepx: binarize x (NCHW f32) -> xq (NHWC i8 +-1) via LDS transpose.
// grid (13 pt, 32 n), 256 thr.
// ---------------------------------------------------------------------------
__global__ __launch_bounds__(256) void prepx(const float* __restrict__ x, signed char* __restrict__ xq) {
    __shared__ __align__(16) int tT[64 * 68];
    int pt = blockIdx.x, n = blockIdx.y;
    int tid = threadIdx.x, lane = tid & 63, wv = tid >> 6;
    int p0 = pt * 64;
    int p = p0 + lane, pc = p < PP ? p : (PP - 1);
#pragma unroll 1
    for (int pp = 0; pp < 16; ++pp) {
        int cb = pp * 16 + wv * 4;
        unsigned word = 0;
#pragma unroll
        for (int j = 0; j < 4; ++j) {
            float val = x[((size_t)n * 256 + cb + j) * PP + pc];
            unsigned byte = (val > 0.0f) ? 0x01u : 0xFFu;
            word |= byte << (8 * j);
        }
        tT[lane * 68 + pp * 4 + wv] = (int)word;
    }
    __syncthreads();
#pragma unroll 1
    for (int pass = 0; pass < 4; ++pass) {
        int s = tid & 15, pq = tid >> 4;
        int pl = pass * 16 + pq;
        int pg = p0 + pl;
        if (pg < PP) {
            v4i w = *(const v4i*)&tT[pl * 68 + s * 4];
            *(v4i*)(xq + ((size_t)n * PP + pg) * 256 + s * 16) = w;
        }
    }
}

// ---------------------------------------------------------------------------
// mconv: binarized 3x3 conv as 9 accumulated i8 GEMMs on the matrix cores.
// grid (196 Mtiles of 128 flat pixels, 4 Nslices of 64 ch), 256 thr (4 waves).
// Wave wid owns 32 pixels x 64 ch = 2 C-tiles (mfma_i32_32x32x32_i8).
// A: flat pixel window [p0-32, p0+160) staged in LDS, 272B row stride
//    (68 words == 4 mod 32 -> b128 reads conflict-free WITHOUT extra swizzle;
//    the round-9 XOR swizzle actually introduced 2-way read conflicts).
// B: contiguous 1KB fragment loads from pre-swizzled wq (L2-resident).
// Output v: NHWC i16. STATS=1: fused exact int BN1 stats via shfl+atomics.
// ---------------------------------------------------------------------------
template<int STATS>
__global__ __launch_bounds__(256) void mconv(const signed char* __restrict__ xq,
        const signed char* __restrict__ wq, short* __restrict__ v,
        int* __restrict__ s1i, u64* __restrict__ s1q) {
    __shared__ __align__(16) signed char lin[52240];   // 192*272 + 16 zero slot
    int tid = threadIdx.x, lane = tid & 63, wid = tid >> 6;
    int kh = lane >> 5, l31 = lane & 31;
    int p0 = blockIdx.x * 128, nbase = blockIdx.y * 64;
    int ps0 = p0 - 32;

    for (int idx = tid; idx < 3072; idx += 256) {      // stage 192 pixels x 256B
        int fpl = idx >> 4, s = idx & 15;
        int fp = ps0 + fpl;
        fp = fp < 0 ? 0 : (fp > NHW - 1 ? NHW - 1 : fp);
        v4i w = *(const v4i*)(xq + (size_t)fp * 256 + s * 16);
        *(v4i*)(lin + fpl * 272 + (s << 4)) = w;
    }
    if (tid < 4) ((int*)(lin + 52224))[tid] = 0;       // zero slot for masked taps
    __syncthreads();

    int p = p0 + wid * 32 + l31;                       // A-row flat pixel
    int pm = p % PP;
    int r = pm / 28, c = pm - r * 28;
    int psl = p - ps0;
    int nb2 = nbase >> 5;
    v16i acc0 = {}; v16i acc1 = {};

#pragma unroll 1
    for (int t = 0; t < 9; ++t) {
        int dr = t / 3, dc = t - dr * 3;
        bool ok = ((unsigned)(c + dc - 1) < 28u) && ((unsigned)(r + dr - 1) < 28u);
        int pslT = psl + (dr - 1) * 28 + (dc - 1);
        int abase = pslT * 272;
        const signed char* wb0 = wq + (size_t)(t * 8 + nb2) * 8192 + (size_t)kh * 512 + (size_t)l31 * 16;
        const signed char* wb1 = wb0 + 8192;
#pragma unroll
        for (int kc = 0; kc < 8; ++kc) {
            int aoff = ok ? (abase + ((kc * 2 + kh) << 4)) : 52224;
            v4i a  = *(const v4i*)(lin + aoff);
            v4i b0 = *(const v4i*)(wb0 + kc * 1024);
            v4i b1 = *(const v4i*)(wb1 + kc * 1024);
            acc0 = __builtin_amdgcn_mfma_i32_32x32x32_i8(a, b0, acc0, 0, 0, 0);
            acc1 = __builtin_amdgcn_mfma_i32_32x32x32_i8(a, b1, acc1, 0, 0, 0);
        }
    }

    // writeback: C/D layout col=lane&31 (ch), row=(j&3)+8*(j>>2)+4*kh (pixel)
    {
        size_t prow = (size_t)(p0 + wid * 32);
        int ch0 = nbase + l31;
#pragma unroll
        for (int j = 0; j < 16; ++j) {
            int row = (j & 3) + 8 * (j >> 2) + 4 * kh;
            size_t off = (prow + row) * 256;
            v[off + ch0]      = (short)acc0[j];
            v[off + ch0 + 32] = (short)acc1[j];
        }
    }
    if (STATS) {
        int ss0 = 0, qq0 = 0, ss1 = 0, qq1 = 0;
#pragma unroll
        for (int j = 0; j < 16; ++j) {
            ss0 += acc0[j]; qq0 += acc0[j] * acc0[j];
            ss1 += acc1[j]; qq1 += acc1[j] * acc1[j];
        }
        ss0 += __shfl_xor(ss0, 32); qq0 += __shfl_xor(qq0, 32);
        ss1 += __shfl_xor(ss1, 32); qq1 += __shfl_xor(qq1, 32);
        if (lane < 32) {
            atomicAdd(&s1i[nbase + lane], ss0);
            atomicAdd(&s1q[nbase + lane], (u64)(unsigned)qq0);
            atomicAdd(&s1i[nbase + 32 + lane], ss1);
            atomicAdd(&s1q[nbase + 32 + lane], (u64)(unsigned)qq1);
        }
    }
}

// ---------------------------------------------------------------------------
// repack: sign(BN1(v1)) -> xq i8 (+-1), NHWC. BN1 params inline from exact
// int stats. grid (98 of 8 pixels, 32 n), 256 thr.
// ---------------------------------------------------------------------------
__global__ __launch_bounds__(256) void repack(const short* __restrict__ v,
        const int* __restrict__ s1i, const u64* __restrict__ s1q,
        const float* __restrict__ gamma, const float* __restrict__ beta,
        signed char* __restrict__ xq) {
    __shared__ float ash[256], bsh[256];
    int tid = threadIdx.x;
    {
        double mean = (double)s1i[tid] * (1.0 / NHW);
        double msq  = (double)s1q[tid] * (1.0 / NHW);
        double var  = msq - mean * mean;
        double istd = 1.0 / sqrt(var + 1e-5);
        double ad   = (double)gamma[tid] * istd;
        ash[tid] = (float)ad;
        bsh[tid] = (float)((double)beta[tid] - mean * ad);
    }
    __syncthreads();
    int n = blockIdx.y;
    int p = blockIdx.x * 8 + (tid >> 5), s8 = tid & 31;
    size_t base = ((size_t)n * PP + p) * 256 + s8 * 8;
    ulonglong2 raw = *(const ulonglong2*)(v + base);
    const short* sp = (const short*)&raw;
    u64 outb = 0;
#pragma unroll
    for (int j = 0; j < 8; ++j) {
        int cc = s8 * 8 + j;
        float y = fmaf(ash[cc], (float)sp[j], bsh[cc]);
        u64 byte = (y > 0.0f) ? 0x01ull : 0xFFull;
        outb |= byte << (8 * j);
    }
    *(u64*)(xq + base) = outb;
}

// ---------------------------------------------------------------------------
// stats2: per-channel partial sums of (v2 + x), NO cross-lane ops.
// grid (7 pslab of 112 pixels, 32 n), 256 thr; thread = channel.
// v NHWC: coalesced 512B rows. x NCHW: per-lane contiguous 448B (float4).
// Partials to scratch; tiny reduce kernel folds 224 partials per channel.
// ---------------------------------------------------------------------------
__global__ __launch_bounds__(256) void stats2(const short* __restrict__ v, const float* __restrict__ x,
                                              double* __restrict__ part) {
    int ps = blockIdx.x, n = blockIdx.y, c = threadIdx.x;
    const short* vb = v + ((size_t)n * PP + ps * 112) * 256 + c;
    const float* xb = x + ((size_t)n * 256 + c) * PP + ps * 112;
    double sd = 0.0, qd = 0.0;
#pragma unroll 1
    for (int i4 = 0; i4 < 28; ++i4) {
        float4 xv = *(const float4*)(xb + i4 * 4);
        float u0 = (float)vb[(size_t)(i4 * 4 + 0) * 256] + xv.x;
        float u1 = (float)vb[(size_t)(i4 * 4 + 1) * 256] + xv.y;
        float u2 = (float)vb[(size_t)(i4 * 4 + 2) * 256] + xv.z;
        float u3 = (float)vb[(size_t)(i4 * 4 + 3) * 256] + xv.w;
        sd += (double)u0 + (double)u1 + (double)u2 + (double)u3;
        qd += (double)u0 * u0 + (double)u1 * u1 + (double)u2 * u2 + (double)u3 * u3;
    }
    size_t o = (size_t)(n * 7 + ps) * 256 + c;
    part[o] = sd;
    part[o + 224 * 256] = qd;
}

__global__ __launch_bounds__(256) void reduce2(const double* __restrict__ part,
                                               double* __restrict__ s2s, double* __restrict__ s2q) {
    int c = threadIdx.x;
    double s = 0.0, q = 0.0;
    for (int k = 0; k < 224; ++k) {
        s += part[(size_t)k * 256 + c];
        q += part[(size_t)(224 + k) * 256 + c];
    }
    s2s[c] = s; s2q[c] = q;
}

// ---------------------------------------------------------------------------
// finalize: out = clip(sc*(v2+x)+bi, -1, 1); BN2 inline; NHWC v -> NCHW out
// via LDS transpose. grid (4 ct, 13 pt, 32 n), 256 thr.
// ---------------------------------------------------------------------------
__global__ __launch_bounds__(256) void finalize(const short* __restrict__ v, const float* __restrict__ x,
        const double* __restrict__ s2s, const double* __restrict__ s2q,
        const float* __restrict__ gamma, const float* __restrict__ beta,
        float* __restrict__ out) {
    __shared__ short t[64 * 66];
    __shared__ float scs[64], bis[64];
    int ct = blockIdx.x, pt = blockIdx.y, n = blockIdx.z, tid = threadIdx.x;
    int c0 = ct * 64, p0 = pt * 64;
    if (tid < 64) {
        int cch = c0 + tid;
        double mean = s2s[cch] * (1.0 / NHW);
        double msq  = s2q[cch] * (1.0 / NHW);
        double var  = msq - mean * mean;
        double istd = 1.0 / sqrt(var + 1e-5);
        double ad   = (double)gamma[cch] * istd;
        scs[tid] = (float)ad;
        bis[tid] = (float)((double)beta[cch] - mean * ad);
    }
    for (int idx = tid; idx < 4096; idx += 256) {
        int i = idx >> 6, cl = idx & 63;
        int pi = p0 + i;
        t[i * 66 + cl] = (pi < PP) ? v[((size_t)n * PP + pi) * 256 + c0 + cl] : (short)0;
    }
    __syncthreads();
    int pl = tid & 63;
    int p = p0 + pl;
    if (p < PP) {
        for (int cl = tid >> 6; cl < 64; cl += 4) {
            int cch = c0 + cl;
            float val = (float)t[pl * 66 + cl] + x[((size_t)n * 256 + cch) * PP + p];
            float rr = fmaf(scs[cl], val, bis[cl]);
            rr = fminf(fmaxf(rr, -1.0f), 1.0f);
            out[((size_t)n * 256 + cch) * PP + p] = rr;
        }
    }
}

// ---------------------------------------------------------------------------
extern "C" void kernel_launch(void* const* d_in, const int* in_sizes, int n_in,
                              void* d_out, int out_size, void* d_ws, size_t ws_size,
                              hipStream_t stream) {
    (void)in_sizes; (void)n_in; (void)out_size; (void)ws_size;
    const float* x   = (const float*)d_in[0];
    const float* w1  = (const float*)d_in[1];
    const float* g1  = (const float*)d_in[2];
    const float* b1  = (const float*)d_in[3];
    const float* w2  = (const float*)d_in[4];
    const float* g2  = (const float*)d_in[5];
    const float* b2  = (const float*)d_in[6];
    float* out = (float*)d_out;

    // scratch in d_out (consumed before finalize overwrites it):
    signed char* xq  = (signed char*)d_out;                 //  6,422,528 B
    signed char* wq1 = (signed char*)d_out + 6422528;       //    589,824 B
    signed char* wq2 = (signed char*)d_out + 7012352;       //    589,824 B (end 7.6MB < 25.7MB)
    // d_ws:
    char* ws = (char*)d_ws;
    short*  v    = (short*)ws;                              // 12,845,056 B
    int*    s1i  = (int*)(ws + 12845056);                   //      1,024 B
    u64*    s1q  = (u64*)(ws + 12846080);                   //      2,048 B
    double* s2s  = (double*)(ws + 12848128);                //      2,048 B
    double* s2q  = (double*)(ws + 12850176);                //      2,048 B
    double* part = (double*)(ws + 12852224);                //    917,504 B

    prepw<<<dim3(2, 256), 256, 0, stream>>>(w1, w2, wq1, wq2, s1i, s1q);
    prepx<<<dim3(13, 32), 256, 0, stream>>>(x, xq);
    mconv<1><<<dim3(196, 4), 256, 0, stream>>>(xq, wq1, v, s1i, s1q);
    repack<<<dim3(98, 32), 256, 0, stream>>>(v, s1i, s1q, g1, b1, xq);
    mconv<0><<<dim3(196, 4), 256, 0, stream>>>(xq, wq2, v, s1i, s1q);
    stats2<<<dim3(7, 32), 256, 0, stream>>>(v, x, part);
    reduce2<<<1, 256, 0, stream>>>(part, s2s, s2q);
    finalize<<<dim3(4, 13, 32), 256, 0, stream>>>(v, x, s2s, s2q, g2, b2, out);
}

// Round 11
// 143.009 us; speedup vs baseline: 2.3934x; 1.0886x over previous
//
#include <hip/hip_runtime.h>
#include <stdint.h>

typedef unsigned long long u64;
typedef int v4i  __attribute__((ext_vector_type(4)));
typedef int v16i __attribute__((ext_vector_type(16)));

#define PP  784
#define NHW 25088

// ---------------------------------------------------------------------------
// prepw: binarize weights into MFMA-B fragment layout + zero stats.
// wq layout: [t][ob=o>>5][kc=k>>5][kh=(k>>4)&1][ol=o&31][k&15] i8 (+-1)
// grid (2 which, 256 o), 256 thr (= cin).
// ---------------------------------------------------------------------------
__global__ __launch_bounds__(256) void prepw(const float* __restrict__ w1, const float* __restrict__ w2,
        signed char* __restrict__ wq1, signed char* __restrict__ wq2,
        int* s1i, u64* s1q) {
    int which = blockIdx.x, o = blockIdx.y, cin = threadIdx.x;
    if (which == 0) {
        if (o == 0) s1i[cin] = 0;
        else if (o == 1) s1q[cin] = 0ull;
    }
    const float* w = which ? w2 : w1;
    signed char* wq = which ? wq2 : wq1;
    int kc = cin >> 5, kh = (cin >> 4) & 1, bx = cin & 15;
    size_t base = (size_t)kc * 1024 + (size_t)kh * 512 + (size_t)(o & 31) * 16 + bx;
    int ob = o >> 5;
#pragma unroll
    for (int t = 0; t < 9; ++t) {
        float val = w[((size_t)o * 256 + cin) * 9 + t];
        wq[(size_t)(t * 8 + ob) * 8192 + base] = (val > 0.0f) ? (signed char)1 : (signed char)-1;
    }
}

// ---------------------------------------------------------------------------
// prepx: binarize x (NCHW f32) -> xq (NHWC i8 +-1) via LDS transpose.
// grid (13 pt, 32 n), 256 thr.
// ---------------------------------------------------------------------------
__global__ __launch_bounds__(256) void prepx(const float* __restrict__ x, signed char* __restrict__ xq) {
    __shared__ __align__(16) int tT[64 * 68];
    int pt = blockIdx.x, n = blockIdx.y;
    int tid = threadIdx.x, lane = tid & 63, wv = tid >> 6;
    int p0 = pt * 64;
    int p = p0 + lane, pc = p < PP ? p : (PP - 1);
#pragma unroll 1
    for (int pp = 0; pp < 16; ++pp) {
        int cb = pp * 16 + wv * 4;
        unsigned word = 0;
#pragma unroll
        for (int j = 0; j < 4; ++j) {
            float val = x[((size_t)n * 256 + cb + j) * PP + pc];
            unsigned byte = (val > 0.0f) ? 0x01u : 0xFFu;
            word |= byte << (8 * j);
        }
        tT[lane * 68 + pp * 4 + wv] = (int)word;
    }
    __syncthreads();
#pragma unroll 1
    for (int pass = 0; pass < 4; ++pass) {
        int s = tid & 15, pq = tid >> 4;
        int pl = pass * 16 + pq;
        int pg = p0 + pl;
        if (pg < PP) {
            v4i w = *(const v4i*)&tT[pl * 68 + s * 4];
            *(v4i*)(xq + ((size_t)n * PP + pg) * 256 + s * 16) = w;
        }
    }
}

// ---------------------------------------------------------------------------
// mconv: binarized 3x3 conv as 9 accumulated i8 GEMMs on the matrix cores,
// SOFTWARE-PIPELINED: all 24 operand fragments (16 B + 8 A) of tap t+1 are
// register-double-buffered and loaded while tap t's 16 MFMAs issue.
// grid (196 Mtiles of 128 flat pixels, 4 Nslices of 64 ch), 256 thr (4 waves).
// waves_per_eu(2,2): VGPR budget 256 (~225 live) -> no load-sinking pressure.
// Edge masking folded into the A-load: astep=0 broadcasts the zero slot.
// ---------------------------------------------------------------------------

#define LOADTAP(B0, B1, A, T) { \
    int dr = (T) / 3, dc = (T) - 3 * dr; \
    bool ok = ((unsigned)(c + dc - 1) < 28u) && ((unsigned)(r + dr - 1) < 28u); \
    int pslT = psl + (dr - 1) * 28 + (dc - 1); \
    int abase = ok ? (pslT * 272 + (kh << 4)) : 52224; \
    int astep = ok ? 32 : 0; \
    const signed char* wb = wbase + (size_t)(T) * 65536; \
    _Pragma("unroll") \
    for (int kc = 0; kc < 8; ++kc) { \
        A[kc]  = *(const v4i*)(lin + abase + kc * astep); \
        B0[kc] = *(const v4i*)(wb + kc * 1024); \
        B1[kc] = *(const v4i*)(wb + 8192 + kc * 1024); \
    } }

#define COMPTAP(B0, B1, A) { \
    _Pragma("unroll") \
    for (int kc = 0; kc < 8; ++kc) { \
        acc0 = __builtin_amdgcn_mfma_i32_32x32x32_i8(A[kc], B0[kc], acc0, 0, 0, 0); \
        acc1 = __builtin_amdgcn_mfma_i32_32x32x32_i8(A[kc], B1[kc], acc1, 0, 0, 0); \
    } }

template<int STATS>
__global__ __attribute__((amdgpu_flat_work_group_size(256, 256), amdgpu_waves_per_eu(2, 2)))
void mconv(const signed char* __restrict__ xq,
        const signed char* __restrict__ wq, short* __restrict__ v,
        int* __restrict__ s1i, u64* __restrict__ s1q) {
    __shared__ __align__(16) signed char lin[52240];   // 192*272 + 16B zero slot
    int tid = threadIdx.x, lane = tid & 63, wid = tid >> 6;
    int kh = lane >> 5, l31 = lane & 31;
    int p0 = blockIdx.x * 128, nbase = blockIdx.y * 64;
    int ps0 = p0 - 32;

    for (int idx = tid; idx < 3072; idx += 256) {      // stage 192 pixels x 256B
        int fpl = idx >> 4, s = idx & 15;
        int fp = ps0 + fpl;
        fp = fp < 0 ? 0 : (fp > NHW - 1 ? NHW - 1 : fp);
        v4i w = *(const v4i*)(xq + (size_t)fp * 256 + s * 16);
        *(v4i*)(lin + fpl * 272 + (s << 4)) = w;
    }
    if (tid < 4) ((int*)(lin + 52224))[tid] = 0;       // zero slot for masked taps
    __syncthreads();

    int p = p0 + wid * 32 + l31;                       // A-row flat pixel
    int pm = p % PP;
    int r = pm / 28, c = pm - r * 28;
    int psl = p - ps0;
    int nb2 = nbase >> 5;
    const signed char* wbase = wq + (size_t)nb2 * 8192 + (size_t)kh * 512 + (size_t)l31 * 16;
    v16i acc0 = {}; v16i acc1 = {};

    v4i b0a[8], b1a[8], aa[8], b0b[8], b1b[8], ab[8];
    LOADTAP(b0a, b1a, aa, 0)
#pragma unroll 1
    for (int m = 0; m < 4; ++m) {
        int t = 2 * m;
        LOADTAP(b0b, b1b, ab, t + 1)
        COMPTAP(b0a, b1a, aa)
        LOADTAP(b0a, b1a, aa, t + 2)
        COMPTAP(b0b, b1b, ab)
    }
    COMPTAP(b0a, b1a, aa)                              // tap 8

    // writeback: C/D layout col=lane&31 (ch), row=(j&3)+8*(j>>2)+4*kh (pixel)
    {
        size_t prow = (size_t)(p0 + wid * 32);
        int ch0 = nbase + l31;
#pragma unroll
        for (int j = 0; j < 16; ++j) {
            int row = (j & 3) + 8 * (j >> 2) + 4 * kh;
            size_t off = (prow + row) * 256;
            v[off + ch0]      = (short)acc0[j];
            v[off + ch0 + 32] = (short)acc1[j];
        }
    }
    if (STATS) {
        int ss0 = 0, qq0 = 0, ss1 = 0, qq1 = 0;
#pragma unroll
        for (int j = 0; j < 16; ++j) {
            ss0 += acc0[j]; qq0 += acc0[j] * acc0[j];
            ss1 += acc1[j]; qq1 += acc1[j] * acc1[j];
        }
        ss0 += __shfl_xor(ss0, 32); qq0 += __shfl_xor(qq0, 32);
        ss1 += __shfl_xor(ss1, 32); qq1 += __shfl_xor(qq1, 32);
        if (lane < 32) {
            atomicAdd(&s1i[nbase + lane], ss0);
            atomicAdd(&s1q[nbase + lane], (u64)(unsigned)qq0);
            atomicAdd(&s1i[nbase + 32 + lane], ss1);
            atomicAdd(&s1q[nbase + 32 + lane], (u64)(unsigned)qq1);
        }
    }
}

// ---------------------------------------------------------------------------
// repack: sign(BN1(v1)) -> xq i8 (+-1), NHWC. BN1 params inline from exact
// int stats. grid (98 of 8 pixels, 32 n), 256 thr.
// ---------------------------------------------------------------------------
__global__ __launch_bounds__(256) void repack(const short* __restrict__ v,
        const int* __restrict__ s1i, const u64* __restrict__ s1q,
        const float* __restrict__ gamma, const float* __restrict__ beta,
        signed char* __restrict__ xq) {
    __shared__ float ash[256], bsh[256];
    int tid = threadIdx.x;
    {
        double mean = (double)s1i[tid] * (1.0 / NHW);
        double msq  = (double)s1q[tid] * (1.0 / NHW);
        double var  = msq - mean * mean;
        double istd = 1.0 / sqrt(var + 1e-5);
        double ad   = (double)gamma[tid] * istd;
        ash[tid] = (float)ad;
        bsh[tid] = (float)((double)beta[tid] - mean * ad);
    }
    __syncthreads();
    int n = blockIdx.y;
    int p = blockIdx.x * 8 + (tid >> 5), s8 = tid & 31;
    size_t base = ((size_t)n * PP + p) * 256 + s8 * 8;
    ulonglong2 raw = *(const ulonglong2*)(v + base);
    const short* sp = (const short*)&raw;
    u64 outb = 0;
#pragma unroll
    for (int j = 0; j < 8; ++j) {
        int cc = s8 * 8 + j;
        float y = fmaf(ash[cc], (float)sp[j], bsh[cc]);
        u64 byte = (y > 0.0f) ? 0x01ull : 0xFFull;
        outb |= byte << (8 * j);
    }
    *(u64*)(xq + base) = outb;
}

// ---------------------------------------------------------------------------
// stats2: per-channel partial sums of (v2 + x), no cross-lane ops.
// grid (7 pslab of 112 pixels, 32 n), 256 thr; thread = channel.
// ---------------------------------------------------------------------------
__global__ __launch_bounds__(256) void stats2(const short* __restrict__ v, const float* __restrict__ x,
                                              double* __restrict__ part) {
    int ps = blockIdx.x, n = blockIdx.y, c = threadIdx.x;
    const short* vb = v + ((size_t)n * PP + ps * 112) * 256 + c;
    const float* xb = x + ((size_t)n * 256 + c) * PP + ps * 112;
    double sd = 0.0, qd = 0.0;
#pragma unroll 1
    for (int i4 = 0; i4 < 28; ++i4) {
        float4 xv = *(const float4*)(xb + i4 * 4);
        float u0 = (float)vb[(size_t)(i4 * 4 + 0) * 256] + xv.x;
        float u1 = (float)vb[(size_t)(i4 * 4 + 1) * 256] + xv.y;
        float u2 = (float)vb[(size_t)(i4 * 4 + 2) * 256] + xv.z;
        float u3 = (float)vb[(size_t)(i4 * 4 + 3) * 256] + xv.w;
        sd += (double)u0 + (double)u1 + (double)u2 + (double)u3;
        qd += (double)u0 * u0 + (double)u1 * u1 + (double)u2 * u2 + (double)u3 * u3;
    }
    size_t o = (size_t)(n * 7 + ps) * 256 + c;
    part[o] = sd;
    part[o + 224 * 256] = qd;
}

__global__ __launch_bounds__(256) void reduce2(const double* __restrict__ part,
                                               double* __restrict__ s2s, double* __restrict__ s2q) {
    int c = threadIdx.x;
    double s = 0.0, q = 0.0;
    for (int k = 0; k < 224; ++k) {
        s += part[(size_t)k * 256 + c];
        q += part[(size_t)(224 + k) * 256 + c];
    }
    s2s[c] = s; s2q[c] = q;
}

// ---------------------------------------------------------------------------
// finalize: out = clip(sc*(v2+x)+bi, -1, 1); BN2 inline; NHWC v -> NCHW out
// via LDS transpose. grid (4 ct, 13 pt, 32 n), 256 thr.
// ---------------------------------------------------------------------------
__global__ __launch_bounds__(256) void finalize(const short* __restrict__ v, const float* __restrict__ x,
        const double* __restrict__ s2s, const double* __restrict__ s2q,
        const float* __restrict__ gamma, const float* __restrict__ beta,
        float* __restrict__ out) {
    __shared__ short t[64 * 66];
    __shared__ float scs[64], bis[64];
    int ct = blockIdx.x, pt = blockIdx.y, n = blockIdx.z, tid = threadIdx.x;
    int c0 = ct * 64, p0 = pt * 64;
    if (tid < 64) {
        int cch = c0 + tid;
        double mean = s2s[cch] * (1.0 / NHW);
        double msq  = s2q[cch] * (1.0 / NHW);
        double var  = msq - mean * mean;
        double istd = 1.0 / sqrt(var + 1e-5);
        double ad   = (double)gamma[cch] * istd;
        scs[tid] = (float)ad;
        bis[tid] = (float)((double)beta[cch] - mean * ad);
    }
    for (int idx = tid; idx < 4096; idx += 256) {
        int i = idx >> 6, cl = idx & 63;
        int pi = p0 + i;
        t[i * 66 + cl] = (pi < PP) ? v[((size_t)n * PP + pi) * 256 + c0 + cl] : (short)0;
    }
    __syncthreads();
    int pl = tid & 63;
    int p = p0 + pl;
    if (p < PP) {
        for (int cl = tid >> 6; cl < 64; cl += 4) {
            int cch = c0 + cl;
            float val = (float)t[pl * 66 + cl] + x[((size_t)n * 256 + cch) * PP + p];
            float rr = fmaf(scs[cl], val, bis[cl]);
            rr = fminf(fmaxf(rr, -1.0f), 1.0f);
            out[((size_t)n * 256 + cch) * PP + p] = rr;
        }
    }
}

// ---------------------------------------------------------------------------
extern "C" void kernel_launch(void* const* d_in, const int* in_sizes, int n_in,
                              void* d_out, int out_size, void* d_ws, size_t ws_size,
                              hipStream_t stream) {
    (void)in_sizes; (void)n_in; (void)out_size; (void)ws_size;
    const float* x   = (const float*)d_in[0];
    const float* w1  = (const float*)d_in[1];
    const float* g1  = (const float*)d_in[2];
    const float* b1  = (const float*)d_in[3];
    const float* w2  = (const float*)d_in[4];
    const float* g2  = (const float*)d_in[5];
    const float* b2  = (const float*)d_in[6];
    float* out = (float*)d_out;

    // scratch in d_out (consumed before finalize overwrites it):
    signed char* xq  = (signed char*)d_out;                 //  6,422,528 B
    signed char* wq1 = (signed char*)d_out + 6422528;       //    589,824 B
    signed char* wq2 = (signed char*)d_out + 7012352;       //    589,824 B
    // d_ws:
    char* ws = (char*)d_ws;
    short*  v    = (short*)ws;                              // 12,845,056 B
    int*    s1i  = (int*)(ws + 12845056);                   //      1,024 B
    u64*    s1q  = (u64*)(ws + 12846080);                   //      2,048 B
    double* s2s  = (double*)(ws + 12848128);                //      2,048 B
    double* s2q  = (double*)(ws + 12850176);                //      2,048 B
    double* part = (double*)(ws + 12852224);                //    917,504 B

    prepw<<<dim3(2, 256), 256, 0, stream>>>(w1, w2, wq1, wq2, s1i, s1q);
    prepx<<<dim3(13, 32), 256, 0, stream>>>(x, xq);
    mconv<1><<<dim3(196, 4), 256, 0, stream>>>(xq, wq1, v, s1i, s1q);
    repack<<<dim3(98, 32), 256, 0, stream>>>(v, s1i, s1q, g1, b1, xq);
    mconv<0><<<dim3(196, 4), 256, 0, stream>>>(xq, wq2, v, s1i, s1q);
    stats2<<<dim3(7, 32), 256, 0, stream>>>(v, x, part);
    reduce2<<<1, 256, 0, stream>>>(part, s2s, s2q);
    finalize<<<dim3(4, 13, 32), 256, 0, stream>>>(v, x, s2s, s2q, g2, b2, out);
}